// Round 5
// baseline (2341.959 us; speedup 1.0000x reference)
//
#include <hip/hip_runtime.h>

#define BATCH 4
#define NPTS  16384
#define CH    128
#define KNN   16

// ---- spatial grid ----
#define G      64
#define GRID3  (G * G * G)          // 262144 cells per batch (= 2^18)
#define GW     0.25f
#define GINVW  4.0f
#define GORIG  (-8.0f)
#define OCCW   (GRID3 / 32)         // 8192 occupancy words per batch

// ---------------- workspace layout (bytes) ----------------
#define XT_OFF    0
#define HT_OFF    33554432
#define CNT_OFF   33554432
#define CUR_OFF   37748736
#define HDR_OFF   41943040
#define OCC_OFF   50331648
#define SPTS_OFF  50462720
#define GCTR_OFF  51511296
#define IDX_OFF   67108864
#define PART_OFF  71303168
#define STATS_OFF 75497472

__device__ __forceinline__ int cell1(float v) {
    int c = (int)floorf((v - GORIG) * GINVW);
    return min(G - 1, max(0, c));
}

// ---------------------------------------------------------------------------
// 0) zero grid counters (counts+cursor contiguous) and per-batch allocators
__global__ __launch_bounds__(256) void zero_kernel(int* __restrict__ p, int n,
                                                   int* __restrict__ gctr) {
    int i = blockIdx.x * 256 + threadIdx.x;
    if (i < BATCH) gctr[i] = 0;
    const int stride = gridDim.x * 256;
    for (; i < n; i += stride) p[i] = 0;
}

// ---------------------------------------------------------------------------
// 1) transpose x [B,CH,N] -> xt [B,N,CH]
__global__ __launch_bounds__(256) void transpose_kernel(const float* __restrict__ x,
                                                        float* __restrict__ xt) {
    __shared__ float t[32][33];
    const int b  = blockIdx.z;
    const int c0 = blockIdx.y * 32;
    const int n0 = blockIdx.x * 32;
    const int tx = threadIdx.x, ty = threadIdx.y;   // block (32,8)
#pragma unroll
    for (int i = 0; i < 4; ++i)
        t[ty + 8 * i][tx] = x[((size_t)b * CH + c0 + ty + 8 * i) * NPTS + n0 + tx];
    __syncthreads();
#pragma unroll
    for (int i = 0; i < 4; ++i)
        xt[((size_t)b * NPTS + n0 + ty + 8 * i) * CH + c0 + tx] = t[tx][ty + 8 * i];
}

// ---------------------------------------------------------------------------
// 2a) count points per cell
__global__ __launch_bounds__(256) void count_kernel(const float* __restrict__ xyz,
                                                    int* __restrict__ counts) {
    const int b = blockIdx.y;
    const int i = blockIdx.x * 256 + threadIdx.x;
    const float* p = xyz + ((size_t)b * NPTS + i) * 3;
    const int c = (cell1(p[2]) * G + cell1(p[1])) * G + cell1(p[0]);
    atomicAdd(&counts[(size_t)b * GRID3 + c], 1);
}

// 2b) per-cell (start,count) headers + occupancy bitmask via wave-aggregated
//     atomic allocation. Cell start order is nondeterministic, but the final
//     knn selection is lexicographic in (d, original_idx) -> output exact.
__global__ __launch_bounds__(256) void cellhdr_kernel(const int* __restrict__ counts,
                                                      int2* __restrict__ hdr,
                                                      unsigned int* __restrict__ occ,
                                                      int* __restrict__ gctr) {
    const int cid  = blockIdx.x * 256 + threadIdx.x;   // 0 .. B*GRID3-1
    const int b    = cid >> 18;
    const int lane = threadIdx.x & 63;
    const int c    = counts[cid];

    // wave-wide inclusive scan of c
    int incl = c;
#pragma unroll
    for (int off = 1; off < 64; off <<= 1) {
        int t = __shfl_up(incl, off);
        if (lane >= off) incl += t;
    }
    const int excl = incl - c;
    const int tot  = __shfl(incl, 63);

    const unsigned long long ball = __ballot(c > 0);
    if (lane == 0) {
        const int w = cid >> 5;     // global word index (= b*OCCW + local)
        occ[w]     = (unsigned int)ball;
        occ[w + 1] = (unsigned int)(ball >> 32);
    }

    int base = 0;
    if (lane == 63) base = atomicAdd(&gctr[b], tot);
    base = __shfl(base, 63);

    if (c > 0) hdr[cid] = make_int2(base + excl, c);
}

// 2c) scatter points into cell-grouped order, original idx in .w
__global__ __launch_bounds__(256) void scatter_kernel(const float* __restrict__ xyz,
                                                      const int2* __restrict__ hdr,
                                                      int* __restrict__ cursor,
                                                      float4* __restrict__ spts) {
    const int b = blockIdx.y;
    const int i = blockIdx.x * 256 + threadIdx.x;
    const float* p = xyz + ((size_t)b * NPTS + i) * 3;
    const float x = p[0], y = p[1], z = p[2];
    const int c = (cell1(z) * G + cell1(y)) * G + cell1(x);
    const int pos = hdr[(size_t)b * GRID3 + c].x + atomicAdd(&cursor[(size_t)b * GRID3 + c], 1);
    spts[(size_t)b * NPTS + pos] = make_float4(x, y, z, __int_as_float(i));
}

// ---------------------------------------------------------------------------
// 2d) exact KNN: 4-lane cooperative per query.
//     Occupied cells round-robin across the group's lanes; per-lane lex-sorted
//     top-16; group bound B = min(lane dq[15]) is provably >= union 16th ->
//     prune/terminate exact. Final: 2 bitonic shuffle-merges -> exact top-16.
__device__ __forceinline__ bool lexlt(float d1, int i1, float d2, int i2) {
    return (d1 < d2) || (d1 == d2 && i1 < i2);
}

template <int XM>
__device__ __forceinline__ void merge_pair(float (&dq)[KNN], int (&iq)[KNN]) {
    float pd[KNN]; int pi[KNN];
#pragma unroll
    for (int t = 0; t < KNN; ++t) {
        pd[t] = __shfl_xor(dq[t], XM);
        pi[t] = __shfl_xor(iq[t], XM);
    }
    // half-cleaner: lower 16 of [A asc, rev(B)] -> bitonic
    float md[KNN]; int mi[KNN];
#pragma unroll
    for (int t = 0; t < KNN; ++t) {
        const float bd = pd[KNN - 1 - t];
        const int   bi = pi[KNN - 1 - t];
        const bool tb = lexlt(bd, bi, dq[t], iq[t]);
        md[t] = tb ? bd : dq[t];
        mi[t] = tb ? bi : iq[t];
    }
    // bitonic merge network, strides 8,4,2,1 (compile-time indices)
#pragma unroll
    for (int d = 8; d >= 1; d >>= 1) {
#pragma unroll
        for (int t = 0; t < KNN; ++t) {
            if ((t & d) == 0) {
                const int u = t | d;
                const bool sw = lexlt(md[u], mi[u], md[t], mi[t]);
                const float ta = sw ? md[u] : md[t];
                const float tb2 = sw ? md[t] : md[u];
                const int   ia = sw ? mi[u] : mi[t];
                const int   ib = sw ? mi[t] : mi[u];
                md[t] = ta; md[u] = tb2; mi[t] = ia; mi[u] = ib;
            }
        }
    }
#pragma unroll
    for (int t = 0; t < KNN; ++t) { dq[t] = md[t]; iq[t] = mi[t]; }
}

__global__ __launch_bounds__(256) void knn_grid_kernel(const float4* __restrict__ spts,
                                                       const int2* __restrict__ hdr,
                                                       const unsigned int* __restrict__ occ,
                                                       int* __restrict__ idx_out) {
    __shared__ unsigned int socc[OCCW];    // 32 KB: this batch's occupancy bits
    const int b   = blockIdx.y;
    const int tid = threadIdx.x;
    for (int i = tid; i < OCCW; i += 256) socc[i] = occ[(size_t)b * OCCW + i];
    __syncthreads();

    const int sub = tid & 3;                      // lane within query group
    const int s   = blockIdx.x * 64 + (tid >> 2); // query slot (sorted order)
    const float4 P = spts[(size_t)b * NPTS + s];
    const float qx = P.x, qy = P.y, qz = P.z;
    const int qi = __float_as_int(P.w);
    const int cx = cell1(qx), cy = cell1(qy), cz = cell1(qz);
    const int2* hb = hdr + (size_t)b * GRID3;
    const float4* pts = spts + (size_t)b * NPTS;

    float dq[KNN]; int iq[KNN];
#pragma unroll
    for (int t = 0; t < KNN; ++t) { dq[t] = 3.0e38f; iq[t] = 0x7fffffff; }
    float B = 3.0e38f;   // group bound (>= union 16th distance)

    for (int R = 0; R < G; ++R) {
        if (R > 0) {
            const int rm = R - 1;
            float dmin = 3.0e38f;
            bool any = false;
            if (cx - rm > 0)     { dmin = fminf(dmin, qx - (GORIG + (cx - rm) * GW)); any = true; }
            if (cx + rm < G - 1) { dmin = fminf(dmin, (GORIG + (cx + rm + 1) * GW) - qx); any = true; }
            if (cy - rm > 0)     { dmin = fminf(dmin, qy - (GORIG + (cy - rm) * GW)); any = true; }
            if (cy + rm < G - 1) { dmin = fminf(dmin, (GORIG + (cy + rm + 1) * GW) - qy); any = true; }
            if (cz - rm > 0)     { dmin = fminf(dmin, qz - (GORIG + (cz - rm) * GW)); any = true; }
            if (cz + rm < G - 1) { dmin = fminf(dmin, (GORIG + (cz + rm + 1) * GW) - qz); any = true; }
            if (!any) break;
            dmin = fmaxf(dmin, 0.0f);
            if (B < dmin * dmin * (1.0f - 1e-5f)) break;
        }
        const int z0 = max(0, cz - R), z1 = min(G - 1, cz + R);
        const int y0 = max(0, cy - R), y1 = min(G - 1, cy + R);
        const int x0 = max(0, cx - R), x1 = min(G - 1, cx + R);
        int cc = 0;     // occupied-cell round-robin counter (uniform in group)
        for (int z = z0; z <= z1; ++z) {
            const int az = (z > cz) ? (z - cz) : (cz - z);
            const float lz = GORIG + z * GW;
            const float dzc = fmaxf(fmaxf(lz - qz, qz - (lz + GW)), 0.0f);
            for (int y = y0; y <= y1; ++y) {
                const int ay = (y > cy) ? (y - cy) : (cy - y);
                const float ly = GORIG + y * GW;
                const float dyc = fmaxf(fmaxf(ly - qy, qy - (ly + GW)), 0.0f);
                const float dzy = dzc * dzc + dyc * dyc;
                const int row = z * G + y;

                unsigned long long m;
                if (az == R || ay == R) {
                    m = (~0ull >> (63 - (x1 - x0))) << x0;       // full face row
                } else {
                    m = 0ull;
                    if (cx - R >= 0) m |= 1ull << (cx - R);
                    if (cx + R < G)  m |= 1ull << (cx + R);
                }
                m &= (unsigned long long)socc[row * 2] |
                     ((unsigned long long)socc[row * 2 + 1] << 32);

                while (m) {
                    const int x = __ffsll(m) - 1;
                    m &= m - 1;
                    const bool mine = ((cc++) & 3) == sub;
                    if (!mine) continue;
                    const float lx = GORIG + x * GW;
                    const float dxc = fmaxf(fmaxf(lx - qx, qx - (lx + GW)), 0.0f);
                    const float cmin = dzy + dxc * dxc;
                    const float pb = fminf(B, dq[KNN - 1]);
                    if (cmin * (1.0f - 1e-5f) > pb) continue;
                    const int2 hc = hb[row * G + x];
                    const int en = hc.x + hc.y;
                    for (int j = hc.x; j < en; ++j) {
                        const float4 pp = pts[j];
                        const float ddx = __fsub_rn(qx, pp.x);
                        const float ddy = __fsub_rn(qy, pp.y);
                        const float ddz = __fsub_rn(qz, pp.z);
                        const float d = __fadd_rn(__fadd_rn(__fmul_rn(ddx, ddx), __fmul_rn(ddy, ddy)),
                                                  __fmul_rn(ddz, ddz));
                        const int oi = __float_as_int(pp.w);
                        if (lexlt(d, oi, dq[KNN - 1], iq[KNN - 1])) {
                            float cd = d; int ci = oi;
#pragma unroll
                            for (int t2 = KNN - 1; t2 >= 1; --t2) {
                                if (lexlt(cd, ci, dq[t2 - 1], iq[t2 - 1])) {
                                    dq[t2] = dq[t2 - 1]; iq[t2] = iq[t2 - 1];
                                    if (t2 == 1) { dq[0] = cd; iq[0] = ci; }
                                } else {
                                    dq[t2] = cd; iq[t2] = ci;
                                    break;
                                }
                            }
                        }
                    }
                }
            }
        }
        // refresh group bound (uniform across the 4 lanes)
        float w15 = dq[KNN - 1];
        w15 = fminf(w15, __shfl_xor(w15, 1));
        w15 = fminf(w15, __shfl_xor(w15, 2));
        B = w15;
    }

    // exact union top-16 via 2 bitonic pair-merges
    merge_pair<1>(dq, iq);
    merge_pair<2>(dq, iq);

    if (sub == 0) {
        int* op = idx_out + ((size_t)b * NPTS + qi) * KNN;
#pragma unroll
        for (int t = 0; t < KNN; ++t) op[t] = iq[t];
    }
}

// ---------------------------------------------------------------------------
// 3) gather + Laplacian dx + 1x1 conv + relu + BN partial sums.
__global__ __launch_bounds__(128) void conv_kernel(const float* __restrict__ xt,
                                                   const int* __restrict__ idx,
                                                   const float* __restrict__ W,
                                                   const float* __restrict__ bias,
                                                   float* __restrict__ h_t,
                                                   float* __restrict__ partials) {
    __shared__ __align__(16) float dxbuf[CH];
    const int o   = threadIdx.x;
    const int blk = blockIdx.x;                  // 0..4095
    const int b   = blk / (NPTS / 16);
    const int n0  = (blk % (NPTS / 16)) * 16;

    float4 w4[CH / 4];
    const float4* wrow = (const float4*)(W + (size_t)o * CH);
#pragma unroll
    for (int i = 0; i < CH / 4; ++i) w4[i] = wrow[i];
    const float bo = bias[o];

    const float* xb = xt + (size_t)b * NPTS * CH;
    float sS = 0.0f, sQ = 0.0f;

    for (int r = 0; r < 16; ++r) {
        const int n = n0 + r;
        const int* ip = idx + ((size_t)b * NPTS + n) * KNN;
        int jj[KNN];
#pragma unroll
        for (int k = 0; k < KNN; ++k) jj[k] = ip[k];
        float va[KNN];
#pragma unroll
        for (int k = 0; k < KNN; ++k) va[k] = xb[(size_t)jj[k] * CH + o];
        const float ctr = xb[(size_t)n * CH + o];
        float acc = 0.0f;
#pragma unroll
        for (int k = 0; k < KNN; ++k) acc += va[k];
        acc -= ctr;

        dxbuf[o] = acc;
        __syncthreads();

        float h = bo;
        const float4* d4 = (const float4*)dxbuf;
#pragma unroll
        for (int cc = 0; cc < CH / 4; ++cc) {
            const float4 a = d4[cc];
            const float4 w = w4[cc];
            h = fmaf(w.x, a.x, h);
            h = fmaf(w.y, a.y, h);
            h = fmaf(w.z, a.z, h);
            h = fmaf(w.w, a.w, h);
        }
        h = fmaxf(h, 0.0f);
        h_t[((size_t)b * NPTS + n) * CH + o] = h;
        sS += h;
        sQ += h * h;
        __syncthreads();
    }

    partials[(size_t)o * 4096 + blk]        = sS;
    partials[(size_t)(CH + o) * 4096 + blk] = sQ;
}

// ---------------------------------------------------------------------------
// 4) reduce partials -> mean / rstd per channel (deterministic)
__global__ __launch_bounds__(256) void bnred_kernel(const float* __restrict__ partials,
                                                    float* __restrict__ stats) {
    const int ch = blockIdx.x;   // 0..127
    const float* pS = partials + (size_t)ch * 4096;
    const float* pQ = partials + (size_t)(CH + ch) * 4096;
    float s = 0.0f, q = 0.0f;
    for (int i = threadIdx.x; i < 4096; i += 256) { s += pS[i]; q += pQ[i]; }
#pragma unroll
    for (int off = 32; off > 0; off >>= 1) {
        s += __shfl_down(s, off);
        q += __shfl_down(q, off);
    }
    __shared__ float wsum[4][2];
    const int wid = threadIdx.x >> 6;
    if ((threadIdx.x & 63) == 0) { wsum[wid][0] = s; wsum[wid][1] = q; }
    __syncthreads();
    if (threadIdx.x == 0) {
        const float S = wsum[0][0] + wsum[1][0] + wsum[2][0] + wsum[3][0];
        const float Q = wsum[0][1] + wsum[1][1] + wsum[2][1] + wsum[3][1];
        const float inv  = 1.0f / (float)(BATCH * NPTS);
        const float mean = S * inv;
        const float var  = Q * inv - mean * mean;
        stats[ch]      = mean;
        stats[CH + ch] = rsqrtf(var + 1e-5f);
    }
}

// ---------------------------------------------------------------------------
// 5) out[b,c,n] = x + gamma*(h - mean)*rstd + beta   (h stored [B,N,CH])
__global__ __launch_bounds__(256) void final_kernel(const float* __restrict__ x,
                                                    const float* __restrict__ h_t,
                                                    const float* __restrict__ stats,
                                                    const float* __restrict__ gamma,
                                                    const float* __restrict__ beta,
                                                    float* __restrict__ out) {
    __shared__ float t[32][33];
    const int b  = blockIdx.z;
    const int o0 = blockIdx.y * 32;
    const int n0 = blockIdx.x * 32;
    const int tx = threadIdx.x, ty = threadIdx.y;   // block (32,8)
#pragma unroll
    for (int i = 0; i < 4; ++i)
        t[ty + 8 * i][tx] = h_t[((size_t)b * NPTS + n0 + ty + 8 * i) * CH + o0 + tx];
    __syncthreads();
#pragma unroll
    for (int i = 0; i < 4; ++i) {
        const int o = o0 + ty + 8 * i;
        const float mean = stats[o];
        const float rstd = stats[CH + o];
        const float g = gamma[o], be = beta[o];
        const size_t offp = ((size_t)b * CH + o) * NPTS + n0 + tx;
        out[offp] = x[offp] + g * ((t[tx][ty + 8 * i] - mean) * rstd) + be;
    }
}

// ---------------------------------------------------------------------------
extern "C" void kernel_launch(void* const* d_in, const int* in_sizes, int n_in,
                              void* d_out, int out_size, void* d_ws, size_t ws_size,
                              hipStream_t stream) {
    const float* xyz    = (const float*)d_in[0];
    const float* x      = (const float*)d_in[1];
    const float* conv_w = (const float*)d_in[2];
    const float* conv_b = (const float*)d_in[3];
    const float* gamma  = (const float*)d_in[4];
    const float* beta   = (const float*)d_in[5];
    float* out = (float*)d_out;

    char* ws = (char*)d_ws;
    float*        xt     = (float*)(ws + XT_OFF);
    int*          counts = (int*)  (ws + CNT_OFF);
    int*          cursor = (int*)  (ws + CUR_OFF);
    int2*         hdr    = (int2*) (ws + HDR_OFF);
    unsigned int* occ    = (unsigned int*)(ws + OCC_OFF);
    float4*       spts   = (float4*)(ws + SPTS_OFF);
    int*          gctr   = (int*)  (ws + GCTR_OFF);
    float*        h_t    = (float*)(ws + HT_OFF);
    int*          idx    = (int*)  (ws + IDX_OFF);
    float*        part   = (float*)(ws + PART_OFF);
    float*        stats  = (float*)(ws + STATS_OFF);

    // feature transpose (independent of grid work)
    transpose_kernel<<<dim3(NPTS / 32, CH / 32, BATCH), dim3(32, 8), 0, stream>>>(x, xt);

    // grid build
    zero_kernel<<<dim3(2048), dim3(256), 0, stream>>>(counts, 2 * BATCH * GRID3, gctr);
    count_kernel<<<dim3(NPTS / 256, BATCH), dim3(256), 0, stream>>>(xyz, counts);
    cellhdr_kernel<<<dim3(BATCH * GRID3 / 256), dim3(256), 0, stream>>>(counts, hdr, occ, gctr);
    scatter_kernel<<<dim3(NPTS / 256, BATCH), dim3(256), 0, stream>>>(xyz, hdr, cursor, spts);

    // exact knn (4-lane cooperative)
    knn_grid_kernel<<<dim3(NPTS / 64, BATCH), dim3(256), 0, stream>>>(spts, hdr, occ, idx);

    // gather + conv + relu + partial BN sums (overwrites grid region with h_t)
    conv_kernel<<<dim3(BATCH * NPTS / 16), dim3(128), 0, stream>>>(xt, idx, conv_w, conv_b, h_t, part);
    bnred_kernel<<<dim3(CH), dim3(256), 0, stream>>>(part, stats);
    final_kernel<<<dim3(NPTS / 32, CH / 32, BATCH), dim3(32, 8), 0, stream>>>(x, h_t, stats, gamma, beta, out);
}

// Round 7
// 1706.160 us; speedup vs baseline: 1.3726x; 1.3726x over previous
//
#include <hip/hip_runtime.h>

#define BATCH 4
#define NPTS  16384
#define CH    128
#define KNN   16

// ---- spatial grid ----
#define G      64
#define GRID3  (G * G * G)          // 262144 cells per batch (= 2^18)
#define GW     0.25f
#define GINVW  4.0f
#define GORIG  (-8.0f)
#define OCCW   (GRID3 / 32)         // 8192 occupancy words per batch

// ---------------- workspace layout (bytes) ----------------
#define XT_OFF    0
#define HT_OFF    33554432
#define CNT_OFF   33554432
#define CUR_OFF   37748736
#define HDR_OFF   41943040
#define OCC_OFF   50331648
#define SPTS_OFF  50462720
#define GCTR_OFF  51511296
#define IDX_OFF   67108864
#define PART_OFF  71303168
#define STATS_OFF 75497472

__device__ __forceinline__ int cell1(float v) {
    int c = (int)floorf((v - GORIG) * GINVW);
    return min(G - 1, max(0, c));
}

// ---------------------------------------------------------------------------
// 0) zero grid counters (counts+cursor contiguous) and per-batch allocators
__global__ __launch_bounds__(256) void zero_kernel(int* __restrict__ p, int n,
                                                   int* __restrict__ gctr) {
    int i = blockIdx.x * 256 + threadIdx.x;
    if (i < BATCH) gctr[i] = 0;
    const int stride = gridDim.x * 256;
    for (; i < n; i += stride) p[i] = 0;
}

// ---------------------------------------------------------------------------
// 1) transpose x [B,CH,N] -> xt [B,N,CH]
__global__ __launch_bounds__(256) void transpose_kernel(const float* __restrict__ x,
                                                        float* __restrict__ xt) {
    __shared__ float t[32][33];
    const int b  = blockIdx.z;
    const int c0 = blockIdx.y * 32;
    const int n0 = blockIdx.x * 32;
    const int tx = threadIdx.x, ty = threadIdx.y;   // block (32,8)
#pragma unroll
    for (int i = 0; i < 4; ++i)
        t[ty + 8 * i][tx] = x[((size_t)b * CH + c0 + ty + 8 * i) * NPTS + n0 + tx];
    __syncthreads();
#pragma unroll
    for (int i = 0; i < 4; ++i)
        xt[((size_t)b * NPTS + n0 + ty + 8 * i) * CH + c0 + tx] = t[tx][ty + 8 * i];
}

// ---------------------------------------------------------------------------
// 2a) count points per cell
__global__ __launch_bounds__(256) void count_kernel(const float* __restrict__ xyz,
                                                    int* __restrict__ counts) {
    const int b = blockIdx.y;
    const int i = blockIdx.x * 256 + threadIdx.x;
    const float* p = xyz + ((size_t)b * NPTS + i) * 3;
    const int c = (cell1(p[2]) * G + cell1(p[1])) * G + cell1(p[0]);
    atomicAdd(&counts[(size_t)b * GRID3 + c], 1);
}

// 2b) per-cell (start,count) headers + occupancy bitmask via wave-aggregated
//     atomic allocation. Cell start order is nondeterministic, but the final
//     knn selection is lexicographic in (d, original_idx) -> output exact.
__global__ __launch_bounds__(256) void cellhdr_kernel(const int* __restrict__ counts,
                                                      int2* __restrict__ hdr,
                                                      unsigned int* __restrict__ occ,
                                                      int* __restrict__ gctr) {
    const int cid  = blockIdx.x * 256 + threadIdx.x;   // 0 .. B*GRID3-1
    const int b    = cid >> 18;
    const int lane = threadIdx.x & 63;
    const int c    = counts[cid];

    // wave-wide inclusive scan of c
    int incl = c;
#pragma unroll
    for (int off = 1; off < 64; off <<= 1) {
        int t = __shfl_up(incl, off);
        if (lane >= off) incl += t;
    }
    const int excl = incl - c;
    const int tot  = __shfl(incl, 63);

    const unsigned long long ball = __ballot(c > 0);
    if (lane == 0) {
        const int w = cid >> 5;     // global word index (= b*OCCW + local)
        occ[w]     = (unsigned int)ball;
        occ[w + 1] = (unsigned int)(ball >> 32);
    }

    int base = 0;
    if (lane == 63) base = atomicAdd(&gctr[b], tot);
    base = __shfl(base, 63);

    if (c > 0) hdr[cid] = make_int2(base + excl, c);
}

// 2c) scatter points into cell-grouped order, original idx in .w
__global__ __launch_bounds__(256) void scatter_kernel(const float* __restrict__ xyz,
                                                      const int2* __restrict__ hdr,
                                                      int* __restrict__ cursor,
                                                      float4* __restrict__ spts) {
    const int b = blockIdx.y;
    const int i = blockIdx.x * 256 + threadIdx.x;
    const float* p = xyz + ((size_t)b * NPTS + i) * 3;
    const float x = p[0], y = p[1], z = p[2];
    const int c = (cell1(z) * G + cell1(y)) * G + cell1(x);
    const int pos = hdr[(size_t)b * GRID3 + c].x + atomicAdd(&cursor[(size_t)b * GRID3 + c], 1);
    spts[(size_t)b * NPTS + pos] = make_float4(x, y, z, __int_as_float(i));
}

// ---------------------------------------------------------------------------
// 2d) exact KNN: 4-lane cooperative per query.
//     Per-lane lists stay DISJOINT the whole kernel (each candidate examined
//     by exactly one lane: point-split ring 0, row-split rings >=1).
//     Shared bound B = union-16th computed on REGISTER COPIES (no write-back,
//     so no duplicate elements ever enter a list). Final merge of disjoint
//     lists -> exact lex-(d,idx) top-16 == jax.lax.top_k order.
__device__ __forceinline__ bool lexlt(float d1, int i1, float d2, int i2) {
    return (d1 < d2) || (d1 == d2 && i1 < i2);
}

template <int XM>
__device__ __forceinline__ void merge_pair(float (&dq)[KNN], int (&iq)[KNN]) {
    float pd[KNN]; int pi[KNN];
#pragma unroll
    for (int t = 0; t < KNN; ++t) {
        pd[t] = __shfl_xor(dq[t], XM);
        pi[t] = __shfl_xor(iq[t], XM);
    }
    // half-cleaner: lower 16 of [A asc, rev(B)] -> bitonic
    float md[KNN]; int mi[KNN];
#pragma unroll
    for (int t = 0; t < KNN; ++t) {
        const float bd = pd[KNN - 1 - t];
        const int   bi = pi[KNN - 1 - t];
        const bool tb = lexlt(bd, bi, dq[t], iq[t]);
        md[t] = tb ? bd : dq[t];
        mi[t] = tb ? bi : iq[t];
    }
    // bitonic merge network, strides 8,4,2,1 (compile-time indices)
#pragma unroll
    for (int d = 8; d >= 1; d >>= 1) {
#pragma unroll
        for (int t = 0; t < KNN; ++t) {
            if ((t & d) == 0) {
                const int u = t | d;
                const bool sw = lexlt(md[u], mi[u], md[t], mi[t]);
                const float ta = sw ? md[u] : md[t];
                const float tb2 = sw ? md[t] : md[u];
                const int   ia = sw ? mi[u] : mi[t];
                const int   ib = sw ? mi[t] : mi[u];
                md[t] = ta; md[u] = tb2; mi[t] = ia; mi[u] = ib;
            }
        }
    }
#pragma unroll
    for (int t = 0; t < KNN; ++t) { dq[t] = md[t]; iq[t] = mi[t]; }
}

// union-16th across the 4 disjoint lane lists, WITHOUT mutating them
__device__ __forceinline__ float group_bound(const float (&dq)[KNN], const int (&iq)[KNN]) {
    float md[KNN]; int mi[KNN];
#pragma unroll
    for (int t = 0; t < KNN; ++t) { md[t] = dq[t]; mi[t] = iq[t]; }
    merge_pair<1>(md, mi);
    merge_pair<2>(md, mi);
    return md[KNN - 1];
}

__global__ __launch_bounds__(256) void knn_grid_kernel(const float4* __restrict__ spts,
                                                       const int2* __restrict__ hdr,
                                                       const unsigned int* __restrict__ occ,
                                                       int* __restrict__ idx_out) {
    __shared__ unsigned int socc[OCCW];    // 32 KB: this batch's occupancy bits
    const int b   = blockIdx.y;
    const int tid = threadIdx.x;
    for (int i = tid; i < OCCW; i += 256) socc[i] = occ[(size_t)b * OCCW + i];
    __syncthreads();

    const int sub = tid & 3;                      // lane within query group
    const int s   = blockIdx.x * 64 + (tid >> 2); // query slot (sorted order)
    const float4 P = spts[(size_t)b * NPTS + s];
    const float qx = P.x, qy = P.y, qz = P.z;
    const int qi = __float_as_int(P.w);
    const int cx = cell1(qx), cy = cell1(qy), cz = cell1(qz);
    const int2* hb = hdr + (size_t)b * GRID3;
    const float4* pts = spts + (size_t)b * NPTS;

    float dq[KNN]; int iq[KNN];
#pragma unroll
    for (int t = 0; t < KNN; ++t) { dq[t] = 3.0e38f; iq[t] = 0x7fffffff; }

    // ---- ring 0: center cell, point-split across the 4 lanes (disjoint) ----
    {
        const int2 hc = hb[(cz * G + cy) * G + cx];
        const int en = hc.x + hc.y;
        for (int j = hc.x + sub; j < en; j += 4) {
            const float4 pp = pts[j];
            const float ddx = __fsub_rn(qx, pp.x);
            const float ddy = __fsub_rn(qy, pp.y);
            const float ddz = __fsub_rn(qz, pp.z);
            const float d = __fadd_rn(__fadd_rn(__fmul_rn(ddx, ddx), __fmul_rn(ddy, ddy)),
                                      __fmul_rn(ddz, ddz));
            const int oi = __float_as_int(pp.w);
            if (lexlt(d, oi, dq[KNN - 1], iq[KNN - 1])) {
                float cd = d; int ci = oi;
#pragma unroll
                for (int t2 = KNN - 1; t2 >= 1; --t2) {
                    if (lexlt(cd, ci, dq[t2 - 1], iq[t2 - 1])) {
                        dq[t2] = dq[t2 - 1]; iq[t2] = iq[t2 - 1];
                        if (t2 == 1) { dq[0] = cd; iq[0] = ci; }
                    } else {
                        dq[t2] = cd; iq[t2] = ci;
                        break;
                    }
                }
            }
        }
    }
    float B = group_bound(dq, iq);   // exact union-16th (3e38 until 16 real)

    for (int R = 1; R < G; ++R) {
        // termination: can anything outside processed box [c-(R-1),c+(R-1)] beat B?
        {
            const int rm = R - 1;
            float dmin = 3.0e38f;
            bool any = false;
            if (cx - rm > 0)     { dmin = fminf(dmin, qx - (GORIG + (cx - rm) * GW)); any = true; }
            if (cx + rm < G - 1) { dmin = fminf(dmin, (GORIG + (cx + rm + 1) * GW) - qx); any = true; }
            if (cy - rm > 0)     { dmin = fminf(dmin, qy - (GORIG + (cy - rm) * GW)); any = true; }
            if (cy + rm < G - 1) { dmin = fminf(dmin, (GORIG + (cy + rm + 1) * GW) - qy); any = true; }
            if (cz - rm > 0)     { dmin = fminf(dmin, qz - (GORIG + (cz - rm) * GW)); any = true; }
            if (cz + rm < G - 1) { dmin = fminf(dmin, (GORIG + (cz + rm + 1) * GW) - qz); any = true; }
            if (!any) break;
            dmin = fmaxf(dmin, 0.0f);
            if (B < dmin * dmin * (1.0f - 1e-5f)) break;
        }
        const int z0 = max(0, cz - R), z1 = min(G - 1, cz + R);
        const int y0 = max(0, cy - R), y1 = min(G - 1, cy + R);
        const int x0 = max(0, cx - R), x1 = min(G - 1, cx + R);
        const int ny = y1 - y0 + 1;
        int ins = 0;
        for (int z = z0; z <= z1; ++z) {
            const int az = (z > cz) ? (z - cz) : (cz - z);
            const int rowbase = (z - z0) * ny - y0;
            const float lz = GORIG + z * GW;
            const float dzc = fmaxf(fmaxf(lz - qz, qz - (lz + GW)), 0.0f);
            for (int y = y0; y <= y1; ++y) {
                if (((rowbase + y) & 3) != sub) continue;   // row ownership (disjoint)
                const int ay = (y > cy) ? (y - cy) : (cy - y);
                const float ly = GORIG + y * GW;
                const float dyc = fmaxf(fmaxf(ly - qy, qy - (ly + GW)), 0.0f);
                const float dzy = dzc * dzc + dyc * dyc;
                const int row = z * G + y;

                unsigned long long m;
                if (az == R || ay == R) {
                    m = (~0ull >> (63 - (x1 - x0))) << x0;       // full face row
                } else {
                    m = 0ull;
                    if (cx - R >= 0) m |= 1ull << (cx - R);
                    if (cx + R < G)  m |= 1ull << (cx + R);
                }
                m &= (unsigned long long)socc[row * 2] |
                     ((unsigned long long)socc[row * 2 + 1] << 32);

                const float pb = fminf(B, dq[KNN - 1]);   // both valid bounds
                while (m) {
                    const int x = __ffsll(m) - 1;
                    m &= m - 1;
                    const float lx = GORIG + x * GW;
                    const float dxc = fmaxf(fmaxf(lx - qx, qx - (lx + GW)), 0.0f);
                    const float cmin = dzy + dxc * dxc;
                    if (cmin * (1.0f - 1e-5f) > fminf(pb, dq[KNN - 1])) continue;
                    const int2 hc = hb[row * G + x];
                    const int en = hc.x + hc.y;
                    for (int j = hc.x; j < en; ++j) {
                        const float4 pp = pts[j];
                        const float ddx = __fsub_rn(qx, pp.x);
                        const float ddy = __fsub_rn(qy, pp.y);
                        const float ddz = __fsub_rn(qz, pp.z);
                        const float d = __fadd_rn(__fadd_rn(__fmul_rn(ddx, ddx), __fmul_rn(ddy, ddy)),
                                                  __fmul_rn(ddz, ddz));
                        const int oi = __float_as_int(pp.w);
                        if (lexlt(d, oi, dq[KNN - 1], iq[KNN - 1])) {
                            ins = 1;
                            float cd = d; int ci = oi;
#pragma unroll
                            for (int t2 = KNN - 1; t2 >= 1; --t2) {
                                if (lexlt(cd, ci, dq[t2 - 1], iq[t2 - 1])) {
                                    dq[t2] = dq[t2 - 1]; iq[t2] = iq[t2 - 1];
                                    if (t2 == 1) { dq[0] = cd; iq[0] = ci; }
                                } else {
                                    dq[t2] = cd; iq[t2] = ci;
                                    break;
                                }
                            }
                        }
                    }
                }
            }
        }
        // refresh exact shared bound if anyone inserted (lists stay disjoint)
        int ia = ins;
        ia |= __shfl_xor(ia, 1);
        ia |= __shfl_xor(ia, 2);
        if (ia) B = group_bound(dq, iq);
    }

    // final exact union top-16 of the 4 DISJOINT lists
    merge_pair<1>(dq, iq);
    merge_pair<2>(dq, iq);

    if (sub == 0) {
        int* op = idx_out + ((size_t)b * NPTS + qi) * KNN;
#pragma unroll
        for (int t = 0; t < KNN; ++t) op[t] = iq[t];
    }
}

// ---------------------------------------------------------------------------
// 3) gather + Laplacian dx + 1x1 conv + relu + BN partial sums.
__global__ __launch_bounds__(128) void conv_kernel(const float* __restrict__ xt,
                                                   const int* __restrict__ idx,
                                                   const float* __restrict__ W,
                                                   const float* __restrict__ bias,
                                                   float* __restrict__ h_t,
                                                   float* __restrict__ partials) {
    __shared__ __align__(16) float dxbuf[CH];
    const int o   = threadIdx.x;
    const int blk = blockIdx.x;                  // 0..4095
    const int b   = blk / (NPTS / 16);
    const int n0  = (blk % (NPTS / 16)) * 16;

    float4 w4[CH / 4];
    const float4* wrow = (const float4*)(W + (size_t)o * CH);
#pragma unroll
    for (int i = 0; i < CH / 4; ++i) w4[i] = wrow[i];
    const float bo = bias[o];

    const float* xb = xt + (size_t)b * NPTS * CH;
    float sS = 0.0f, sQ = 0.0f;

    for (int r = 0; r < 16; ++r) {
        const int n = n0 + r;
        const int* ip = idx + ((size_t)b * NPTS + n) * KNN;
        int jj[KNN];
#pragma unroll
        for (int k = 0; k < KNN; ++k) jj[k] = ip[k];
        float va[KNN];
#pragma unroll
        for (int k = 0; k < KNN; ++k) va[k] = xb[(size_t)jj[k] * CH + o];
        const float ctr = xb[(size_t)n * CH + o];
        float acc = 0.0f;
#pragma unroll
        for (int k = 0; k < KNN; ++k) acc += va[k];
        acc -= ctr;

        dxbuf[o] = acc;
        __syncthreads();

        float h = bo;
        const float4* d4 = (const float4*)dxbuf;
#pragma unroll
        for (int cc = 0; cc < CH / 4; ++cc) {
            const float4 a = d4[cc];
            const float4 w = w4[cc];
            h = fmaf(w.x, a.x, h);
            h = fmaf(w.y, a.y, h);
            h = fmaf(w.z, a.z, h);
            h = fmaf(w.w, a.w, h);
        }
        h = fmaxf(h, 0.0f);
        h_t[((size_t)b * NPTS + n) * CH + o] = h;
        sS += h;
        sQ += h * h;
        __syncthreads();
    }

    partials[(size_t)o * 4096 + blk]        = sS;
    partials[(size_t)(CH + o) * 4096 + blk] = sQ;
}

// ---------------------------------------------------------------------------
// 4) reduce partials -> mean / rstd per channel (deterministic)
__global__ __launch_bounds__(256) void bnred_kernel(const float* __restrict__ partials,
                                                    float* __restrict__ stats) {
    const int ch = blockIdx.x;   // 0..127
    const float* pS = partials + (size_t)ch * 4096;
    const float* pQ = partials + (size_t)(CH + ch) * 4096;
    float s = 0.0f, q = 0.0f;
    for (int i = threadIdx.x; i < 4096; i += 256) { s += pS[i]; q += pQ[i]; }
#pragma unroll
    for (int off = 32; off > 0; off >>= 1) {
        s += __shfl_down(s, off);
        q += __shfl_down(q, off);
    }
    __shared__ float wsum[4][2];
    const int wid = threadIdx.x >> 6;
    if ((threadIdx.x & 63) == 0) { wsum[wid][0] = s; wsum[wid][1] = q; }
    __syncthreads();
    if (threadIdx.x == 0) {
        const float S = wsum[0][0] + wsum[1][0] + wsum[2][0] + wsum[3][0];
        const float Q = wsum[0][1] + wsum[1][1] + wsum[2][1] + wsum[3][1];
        const float inv  = 1.0f / (float)(BATCH * NPTS);
        const float mean = S * inv;
        const float var  = Q * inv - mean * mean;
        stats[ch]      = mean;
        stats[CH + ch] = rsqrtf(var + 1e-5f);
    }
}

// ---------------------------------------------------------------------------
// 5) out[b,c,n] = x + gamma*(h - mean)*rstd + beta   (h stored [B,N,CH])
__global__ __launch_bounds__(256) void final_kernel(const float* __restrict__ x,
                                                    const float* __restrict__ h_t,
                                                    const float* __restrict__ stats,
                                                    const float* __restrict__ gamma,
                                                    const float* __restrict__ beta,
                                                    float* __restrict__ out) {
    __shared__ float t[32][33];
    const int b  = blockIdx.z;
    const int o0 = blockIdx.y * 32;
    const int n0 = blockIdx.x * 32;
    const int tx = threadIdx.x, ty = threadIdx.y;   // block (32,8)
#pragma unroll
    for (int i = 0; i < 4; ++i)
        t[ty + 8 * i][tx] = h_t[((size_t)b * NPTS + n0 + ty + 8 * i) * CH + o0 + tx];
    __syncthreads();
#pragma unroll
    for (int i = 0; i < 4; ++i) {
        const int o = o0 + ty + 8 * i;
        const float mean = stats[o];
        const float rstd = stats[CH + o];
        const float g = gamma[o], be = beta[o];
        const size_t offp = ((size_t)b * CH + o) * NPTS + n0 + tx;
        out[offp] = x[offp] + g * ((t[tx][ty + 8 * i] - mean) * rstd) + be;
    }
}

// ---------------------------------------------------------------------------
extern "C" void kernel_launch(void* const* d_in, const int* in_sizes, int n_in,
                              void* d_out, int out_size, void* d_ws, size_t ws_size,
                              hipStream_t stream) {
    const float* xyz    = (const float*)d_in[0];
    const float* x      = (const float*)d_in[1];
    const float* conv_w = (const float*)d_in[2];
    const float* conv_b = (const float*)d_in[3];
    const float* gamma  = (const float*)d_in[4];
    const float* beta   = (const float*)d_in[5];
    float* out = (float*)d_out;

    char* ws = (char*)d_ws;
    float*        xt     = (float*)(ws + XT_OFF);
    int*          counts = (int*)  (ws + CNT_OFF);
    int*          cursor = (int*)  (ws + CUR_OFF);
    int2*         hdr    = (int2*) (ws + HDR_OFF);
    unsigned int* occ    = (unsigned int*)(ws + OCC_OFF);
    float4*       spts   = (float4*)(ws + SPTS_OFF);
    int*          gctr   = (int*)  (ws + GCTR_OFF);
    float*        h_t    = (float*)(ws + HT_OFF);
    int*          idx    = (int*)  (ws + IDX_OFF);
    float*        part   = (float*)(ws + PART_OFF);
    float*        stats  = (float*)(ws + STATS_OFF);

    // feature transpose (independent of grid work)
    transpose_kernel<<<dim3(NPTS / 32, CH / 32, BATCH), dim3(32, 8), 0, stream>>>(x, xt);

    // grid build
    zero_kernel<<<dim3(2048), dim3(256), 0, stream>>>(counts, 2 * BATCH * GRID3, gctr);
    count_kernel<<<dim3(NPTS / 256, BATCH), dim3(256), 0, stream>>>(xyz, counts);
    cellhdr_kernel<<<dim3(BATCH * GRID3 / 256), dim3(256), 0, stream>>>(counts, hdr, occ, gctr);
    scatter_kernel<<<dim3(NPTS / 256, BATCH), dim3(256), 0, stream>>>(xyz, hdr, cursor, spts);

    // exact knn (4-lane cooperative, disjoint lists + exact shared bound)
    knn_grid_kernel<<<dim3(NPTS / 64, BATCH), dim3(256), 0, stream>>>(spts, hdr, occ, idx);

    // gather + conv + relu + partial BN sums (overwrites grid region with h_t)
    conv_kernel<<<dim3(BATCH * NPTS / 16), dim3(128), 0, stream>>>(xt, idx, conv_w, conv_b, h_t, part);
    bnred_kernel<<<dim3(CH), dim3(256), 0, stream>>>(part, stats);
    final_kernel<<<dim3(NPTS / 32, CH / 32, BATCH), dim3(32, 8), 0, stream>>>(x, h_t, stats, gamma, beta, out);
}

// Round 8
// 1516.249 us; speedup vs baseline: 1.5446x; 1.1253x over previous
//
#include <hip/hip_runtime.h>

#define BATCH 4
#define NPTS  16384
#define CH    128
#define KNN   16

// ---- fine grid: 64^3 cells of 0.25 ----
#define G      64
#define GRID3  (G * G * G)          // 262144 cells per batch (= 2^18)
#define GW     0.25f
#define GINVW  4.0f
#define GORIG  (-8.0f)
#define OCCW   (GRID3 / 32)         // 8192 fine occupancy words per batch
// ---- coarse grid: 16^3 cells of 1.0 (4x4x4 fine) ----
#define GC     16
#define GRIDC3 (GC * GC * GC)       // 4096 coarse cells per batch
#define GWC    1.0f
#define CROWS  (GC * GC)            // 256 coarse rows (16 x-bits each)
#define COARSE_THR 32               // center coarse count < THR -> coarse walk

// ---------------- workspace layout (bytes) ----------------
// xt    : [B][N][CH] float     off 0            33,554,432
// grid region (reused later by h_t, written only after knn done):
//   counts : [B][G^3] int      off 33554432      4,194,304
//   cursor : [B][G^3] int      off 37748736      4,194,304
//   hdr    : [B][G^3] int2     off 41943040      8,388,608   (permuted cid)
//   hdrc   : [B][GC^3] int2    off 50331648        131,072
//   occ    : [B][8192] uint    off 50462720        131,072   (linear rows)
//   soccc  : [B][256] uint     off 50593792          4,096
//   spts   : [B][N] float4     off 50597888      1,048,576
//   gctr   : [B] int           off 51646464             16
// idx   : [B][N][16] int       off 67108864      4,194,304
// part  : [256][4096] float    off 71303168      4,194,304
// stats : [256] float          off 75497472          1,024
#define XT_OFF    0
#define HT_OFF    33554432
#define CNT_OFF   33554432
#define CUR_OFF   37748736
#define HDR_OFF   41943040
#define HDRC_OFF  50331648
#define OCC_OFF   50462720
#define SOCCC_OFF 50593792
#define SPTS_OFF  50597888
#define GCTR_OFF  51646464
#define IDX_OFF   67108864
#define PART_OFF  71303168
#define STATS_OFF 75497472

__device__ __forceinline__ int cell1(float v) {
    int c = (int)floorf((v - GORIG) * GINVW);
    return min(G - 1, max(0, c));
}

// permuted (coarse-major) fine cell id within a batch
__device__ __forceinline__ int pcid_of(int z, int y, int x) {
    const int cc  = ((z >> 2) * GC + (y >> 2)) * GC + (x >> 2);
    const int loc = ((z & 3) * 4 + (y & 3)) * 4 + (x & 3);
    return cc * 64 + loc;
}

__device__ __forceinline__ bool lexlt(float d1, int i1, float d2, int i2) {
    return (d1 < d2) || (d1 == d2 && i1 < i2);
}

__device__ __forceinline__ void insert_lex(float (&dq)[KNN], int (&iq)[KNN], float d, int oi) {
    if (!lexlt(d, oi, dq[KNN - 1], iq[KNN - 1])) return;
    float cd = d; int ci = oi;
#pragma unroll
    for (int t = KNN - 1; t >= 1; --t) {
        if (lexlt(cd, ci, dq[t - 1], iq[t - 1])) {
            dq[t] = dq[t - 1]; iq[t] = iq[t - 1];
            if (t == 1) { dq[0] = cd; iq[0] = ci; }
        } else {
            dq[t] = cd; iq[t] = ci;
            break;
        }
    }
}

__device__ __forceinline__ void scan_cell(const float4* __restrict__ pts, int st, int en,
                                          float qx, float qy, float qz,
                                          float (&dq)[KNN], int (&iq)[KNN]) {
    for (int j = st; j < en; ++j) {
        const float4 pp = pts[j];
        const float ddx = __fsub_rn(qx, pp.x);
        const float ddy = __fsub_rn(qy, pp.y);
        const float ddz = __fsub_rn(qz, pp.z);
        const float d = __fadd_rn(__fadd_rn(__fmul_rn(ddx, ddx), __fmul_rn(ddy, ddy)),
                                  __fmul_rn(ddz, ddz));
        insert_lex(dq, iq, d, __float_as_int(pp.w));
    }
}

// ---------------------------------------------------------------------------
// 0) zero: counts+cursor (p,n), soccc (p2,n2), gctr
__global__ __launch_bounds__(256) void zero_kernel(int* __restrict__ p, int n,
                                                   int* __restrict__ p2, int n2,
                                                   int* __restrict__ gctr) {
    int i = blockIdx.x * 256 + threadIdx.x;
    if (i < BATCH) gctr[i] = 0;
    if (i < n2) p2[i] = 0;
    const int stride = gridDim.x * 256;
    for (; i < n; i += stride) p[i] = 0;
}

// ---------------------------------------------------------------------------
// 1) transpose x [B,CH,N] -> xt [B,N,CH]
__global__ __launch_bounds__(256) void transpose_kernel(const float* __restrict__ x,
                                                        float* __restrict__ xt) {
    __shared__ float t[32][33];
    const int b  = blockIdx.z;
    const int c0 = blockIdx.y * 32;
    const int n0 = blockIdx.x * 32;
    const int tx = threadIdx.x, ty = threadIdx.y;   // block (32,8)
#pragma unroll
    for (int i = 0; i < 4; ++i)
        t[ty + 8 * i][tx] = x[((size_t)b * CH + c0 + ty + 8 * i) * NPTS + n0 + tx];
    __syncthreads();
#pragma unroll
    for (int i = 0; i < 4; ++i)
        xt[((size_t)b * NPTS + n0 + ty + 8 * i) * CH + c0 + tx] = t[tx][ty + 8 * i];
}

// ---------------------------------------------------------------------------
// 2a) count points per (permuted) fine cell
__global__ __launch_bounds__(256) void count_kernel(const float* __restrict__ xyz,
                                                    int* __restrict__ counts) {
    const int b = blockIdx.y;
    const int i = blockIdx.x * 256 + threadIdx.x;
    const float* p = xyz + ((size_t)b * NPTS + i) * 3;
    const int c = pcid_of(cell1(p[2]), cell1(p[1]), cell1(p[0]));
    atomicAdd(&counts[((size_t)b << 18) + c], 1);
}

// 2b) headers: one wave = one coarse cell (64 fine cells, contiguous pcids).
//     Wave scan -> fine offsets; one atomicAdd per coarse cell -> coarse base.
//     Coarse occupancy bit via atomicOr. Allocation order nondeterministic,
//     but knn selection is lexicographic (d, original idx) -> output exact.
__global__ __launch_bounds__(256) void cellhdr_kernel(const int* __restrict__ counts,
                                                      int2* __restrict__ hdr,
                                                      int2* __restrict__ hdrc,
                                                      unsigned int* __restrict__ soccc,
                                                      int* __restrict__ gctr) {
    const int pcid = blockIdx.x * 256 + threadIdx.x;   // global permuted cid
    const int b    = pcid >> 18;
    const int lane = threadIdx.x & 63;
    const int c    = counts[pcid];

    int incl = c;
#pragma unroll
    for (int off = 1; off < 64; off <<= 1) {
        int t = __shfl_up(incl, off);
        if (lane >= off) incl += t;
    }
    const int excl = incl - c;
    const int tot  = __shfl(incl, 63);

    int base = 0;
    if (lane == 63) base = atomicAdd(&gctr[b], tot);
    base = __shfl(base, 63);

    if (c > 0) hdr[pcid] = make_int2(base + excl, c);

    if (lane == 63 && tot > 0) {
        const int ccg = pcid >> 6;                 // global coarse cell
        const int cc  = ccg & (GRIDC3 - 1);        // within batch
        hdrc[ccg] = make_int2(base, tot);
        const int xc  = cc & (GC - 1);
        const int row = cc >> 4;                   // zc*16+yc
        atomicOr(&soccc[b * CROWS + row], 1u << xc);
    }
}

// 2c) fine occupancy bitmask in LINEAR (z,y,x) layout: wave = one x-row
__global__ __launch_bounds__(256) void occ_kernel(const int* __restrict__ counts,
                                                  unsigned int* __restrict__ occ) {
    const int lcid = blockIdx.x * 256 + threadIdx.x;   // b<<18 | z<<12 | y<<6 | x
    const int b = lcid >> 18;
    const int lin = lcid & (GRID3 - 1);
    const int z = lin >> 12, y = (lin >> 6) & 63, x = lin & 63;
    const int c = counts[((size_t)b << 18) + pcid_of(z, y, x)];
    const unsigned long long ball = __ballot(c > 0);
    if ((threadIdx.x & 63) == 0) {
        const int row = lcid >> 6;                 // b*4096 + z*64+y
        occ[row * 2]     = (unsigned int)ball;
        occ[row * 2 + 1] = (unsigned int)(ball >> 32);
    }
}

// 2d) scatter points into cell-grouped order, original idx in .w
__global__ __launch_bounds__(256) void scatter_kernel(const float* __restrict__ xyz,
                                                      const int2* __restrict__ hdr,
                                                      int* __restrict__ cursor,
                                                      float4* __restrict__ spts) {
    const int b = blockIdx.y;
    const int i = blockIdx.x * 256 + threadIdx.x;
    const float* p = xyz + ((size_t)b * NPTS + i) * 3;
    const float x = p[0], y = p[1], z = p[2];
    const int c = pcid_of(cell1(z), cell1(y), cell1(x));
    const int pos = hdr[((size_t)b << 18) + c].x + atomicAdd(&cursor[((size_t)b << 18) + c], 1);
    spts[(size_t)b * NPTS + pos] = make_float4(x, y, z, __int_as_float(i));
}

// ---------------------------------------------------------------------------
// 2e) exact KNN, serial walk per thread, TWO-LEVEL: dense queries walk the
//     fine grid; sparse queries (center coarse cell count < THR) walk the
//     coarse grid. Both are the same exact ring algorithm (cell min-dist
//     prune + outside-box termination), so output == jax.lax.top_k exactly.
__global__ __launch_bounds__(256) void knn_grid_kernel(const float4* __restrict__ spts,
                                                       const int2* __restrict__ hdr,
                                                       const int2* __restrict__ hdrc,
                                                       const unsigned int* __restrict__ occ,
                                                       const unsigned int* __restrict__ soccc,
                                                       int* __restrict__ idx_out) {
    __shared__ unsigned int socc[OCCW];     // 32 KB fine occupancy (linear rows)
    __shared__ unsigned int scc[CROWS];     // 1 KB coarse occupancy
    const int b   = blockIdx.y;
    const int tid = threadIdx.x;
    for (int i = tid; i < OCCW; i += 256) socc[i] = occ[(size_t)b * OCCW + i];
    if (tid < CROWS) scc[tid] = soccc[b * CROWS + tid];
    __syncthreads();

    const int s = blockIdx.x * 256 + tid;
    const float4 P = spts[(size_t)b * NPTS + s];
    const float qx = P.x, qy = P.y, qz = P.z;
    const int qi = __float_as_int(P.w);
    const int cx = cell1(qx), cy = cell1(qy), cz = cell1(qz);
    const int2* hb  = hdr  + ((size_t)b << 18);
    const int2* hbc = hdrc + (size_t)b * GRIDC3;
    const float4* pts = spts + (size_t)b * NPTS;

    float dq[KNN]; int iq[KNN];
#pragma unroll
    for (int t = 0; t < KNN; ++t) { dq[t] = 3.0e38f; iq[t] = 0x7fffffff; }

    // level decision from center coarse cell occupancy/count
    const int cxc = cx >> 2, cyc = cy >> 2, czc = cz >> 2;
    const int ccq = (czc * GC + cyc) * GC + cxc;
    const int crow = ccq >> 4;
    int centerCnt = 0;
    if ((scc[crow] >> (ccq & 15)) & 1u) centerCnt = hbc[ccq].y;

    if (centerCnt >= COARSE_THR) {
        // ================= FINE WALK (R4-proven) =================
        {
            const int2 hc = hb[pcid_of(cz, cy, cx)];
            scan_cell(pts, hc.x, hc.x + hc.y, qx, qy, qz, dq, iq);
        }
        for (int R = 1; R < G; ++R) {
            const int rm = R - 1;
            float dmin = 3.0e38f;
            bool any = false;
            if (cx - rm > 0)     { dmin = fminf(dmin, qx - (GORIG + (cx - rm) * GW)); any = true; }
            if (cx + rm < G - 1) { dmin = fminf(dmin, (GORIG + (cx + rm + 1) * GW) - qx); any = true; }
            if (cy - rm > 0)     { dmin = fminf(dmin, qy - (GORIG + (cy - rm) * GW)); any = true; }
            if (cy + rm < G - 1) { dmin = fminf(dmin, (GORIG + (cy + rm + 1) * GW) - qy); any = true; }
            if (cz - rm > 0)     { dmin = fminf(dmin, qz - (GORIG + (cz - rm) * GW)); any = true; }
            if (cz + rm < G - 1) { dmin = fminf(dmin, (GORIG + (cz + rm + 1) * GW) - qz); any = true; }
            if (!any) break;
            dmin = fmaxf(dmin, 0.0f);
            if (dq[KNN - 1] < dmin * dmin * (1.0f - 1e-5f)) break;

            const int z0 = max(0, cz - R), z1 = min(G - 1, cz + R);
            const int y0 = max(0, cy - R), y1 = min(G - 1, cy + R);
            const int x0 = max(0, cx - R), x1 = min(G - 1, cx + R);
            for (int z = z0; z <= z1; ++z) {
                const int az = (z > cz) ? (z - cz) : (cz - z);
                const float lz = GORIG + z * GW;
                const float dzc = fmaxf(fmaxf(lz - qz, qz - (lz + GW)), 0.0f);
                for (int y = y0; y <= y1; ++y) {
                    const int ay = (y > cy) ? (y - cy) : (cy - y);
                    const float ly = GORIG + y * GW;
                    const float dyc = fmaxf(fmaxf(ly - qy, qy - (ly + GW)), 0.0f);
                    const float dzy = dzc * dzc + dyc * dyc;
                    const int row = z * G + y;

                    unsigned long long m;
                    if (az == R || ay == R) {
                        m = (~0ull >> (63 - (x1 - x0))) << x0;
                    } else {
                        m = 0ull;
                        if (cx - R >= 0) m |= 1ull << (cx - R);
                        if (cx + R < G)  m |= 1ull << (cx + R);
                    }
                    m &= (unsigned long long)socc[row * 2] |
                         ((unsigned long long)socc[row * 2 + 1] << 32);

                    while (m) {
                        const int x = __ffsll(m) - 1;
                        m &= m - 1;
                        const float lx = GORIG + x * GW;
                        const float dxc = fmaxf(fmaxf(lx - qx, qx - (lx + GW)), 0.0f);
                        const float cmin = dzy + dxc * dxc;
                        if (cmin * (1.0f - 1e-5f) > dq[KNN - 1]) continue;
                        const int2 hc = hb[pcid_of(z, y, x)];
                        scan_cell(pts, hc.x, hc.x + hc.y, qx, qy, qz, dq, iq);
                    }
                }
            }
        }
    } else {
        // ================= COARSE WALK (sparse region) =================
        if (centerCnt > 0) {
            const int2 hc = hbc[ccq];
            scan_cell(pts, hc.x, hc.x + hc.y, qx, qy, qz, dq, iq);
        }
        for (int R = 1; R < GC; ++R) {
            const int rm = R - 1;
            float dmin = 3.0e38f;
            bool any = false;
            if (cxc - rm > 0)      { dmin = fminf(dmin, qx - (GORIG + (cxc - rm) * GWC)); any = true; }
            if (cxc + rm < GC - 1) { dmin = fminf(dmin, (GORIG + (cxc + rm + 1) * GWC) - qx); any = true; }
            if (cyc - rm > 0)      { dmin = fminf(dmin, qy - (GORIG + (cyc - rm) * GWC)); any = true; }
            if (cyc + rm < GC - 1) { dmin = fminf(dmin, (GORIG + (cyc + rm + 1) * GWC) - qy); any = true; }
            if (czc - rm > 0)      { dmin = fminf(dmin, qz - (GORIG + (czc - rm) * GWC)); any = true; }
            if (czc + rm < GC - 1) { dmin = fminf(dmin, (GORIG + (czc + rm + 1) * GWC) - qz); any = true; }
            if (!any) break;
            dmin = fmaxf(dmin, 0.0f);
            if (dq[KNN - 1] < dmin * dmin * (1.0f - 1e-5f)) break;

            const int z0 = max(0, czc - R), z1 = min(GC - 1, czc + R);
            const int y0 = max(0, cyc - R), y1 = min(GC - 1, cyc + R);
            const int x0 = max(0, cxc - R), x1 = min(GC - 1, cxc + R);
            for (int z = z0; z <= z1; ++z) {
                const int az = (z > czc) ? (z - czc) : (czc - z);
                const float lz = GORIG + z * GWC;
                const float dzc2 = fmaxf(fmaxf(lz - qz, qz - (lz + GWC)), 0.0f);
                for (int y = y0; y <= y1; ++y) {
                    const int ay = (y > cyc) ? (y - cyc) : (cyc - y);
                    const float ly = GORIG + y * GWC;
                    const float dyc = fmaxf(fmaxf(ly - qy, qy - (ly + GWC)), 0.0f);
                    const float dzy = dzc2 * dzc2 + dyc * dyc;
                    const int row = z * GC + y;

                    unsigned int m;
                    if (az == R || ay == R) {
                        m = ((x1 - x0 == 15) ? 0xFFFFu : ((1u << (x1 - x0 + 1)) - 1u)) << x0;
                    } else {
                        m = 0u;
                        if (cxc - R >= 0) m |= 1u << (cxc - R);
                        if (cxc + R < GC) m |= 1u << (cxc + R);
                    }
                    m &= scc[row];

                    while (m) {
                        const int x = __ffs(m) - 1;
                        m &= m - 1;
                        const float lx = GORIG + x * GWC;
                        const float dxc = fmaxf(fmaxf(lx - qx, qx - (lx + GWC)), 0.0f);
                        const float cmin = dzy + dxc * dxc;
                        if (cmin * (1.0f - 1e-5f) > dq[KNN - 1]) continue;
                        const int2 hc = hbc[row * GC + x];
                        scan_cell(pts, hc.x, hc.x + hc.y, qx, qy, qz, dq, iq);
                    }
                }
            }
        }
    }

    int* op = idx_out + ((size_t)b * NPTS + qi) * KNN;
#pragma unroll
    for (int t = 0; t < KNN; ++t) op[t] = iq[t];
}

// ---------------------------------------------------------------------------
// 3) gather + Laplacian dx + 1x1 conv + relu + BN partial sums.
__global__ __launch_bounds__(128) void conv_kernel(const float* __restrict__ xt,
                                                   const int* __restrict__ idx,
                                                   const float* __restrict__ W,
                                                   const float* __restrict__ bias,
                                                   float* __restrict__ h_t,
                                                   float* __restrict__ partials) {
    __shared__ __align__(16) float dxbuf[CH];
    const int o   = threadIdx.x;
    const int blk = blockIdx.x;                  // 0..4095
    const int b   = blk / (NPTS / 16);
    const int n0  = (blk % (NPTS / 16)) * 16;

    float4 w4[CH / 4];
    const float4* wrow = (const float4*)(W + (size_t)o * CH);
#pragma unroll
    for (int i = 0; i < CH / 4; ++i) w4[i] = wrow[i];
    const float bo = bias[o];

    const float* xb = xt + (size_t)b * NPTS * CH;
    float sS = 0.0f, sQ = 0.0f;

    for (int r = 0; r < 16; ++r) {
        const int n = n0 + r;
        const int* ip = idx + ((size_t)b * NPTS + n) * KNN;
        int jj[KNN];
#pragma unroll
        for (int k = 0; k < KNN; ++k) jj[k] = ip[k];
        float va[KNN];
#pragma unroll
        for (int k = 0; k < KNN; ++k) va[k] = xb[(size_t)jj[k] * CH + o];
        const float ctr = xb[(size_t)n * CH + o];
        float acc = 0.0f;
#pragma unroll
        for (int k = 0; k < KNN; ++k) acc += va[k];
        acc -= ctr;

        dxbuf[o] = acc;
        __syncthreads();

        float h = bo;
        const float4* d4 = (const float4*)dxbuf;
#pragma unroll
        for (int cc = 0; cc < CH / 4; ++cc) {
            const float4 a = d4[cc];
            const float4 w = w4[cc];
            h = fmaf(w.x, a.x, h);
            h = fmaf(w.y, a.y, h);
            h = fmaf(w.z, a.z, h);
            h = fmaf(w.w, a.w, h);
        }
        h = fmaxf(h, 0.0f);
        h_t[((size_t)b * NPTS + n) * CH + o] = h;
        sS += h;
        sQ += h * h;
        __syncthreads();
    }

    partials[(size_t)o * 4096 + blk]        = sS;
    partials[(size_t)(CH + o) * 4096 + blk] = sQ;
}

// ---------------------------------------------------------------------------
// 4) reduce partials -> mean / rstd per channel (deterministic)
__global__ __launch_bounds__(256) void bnred_kernel(const float* __restrict__ partials,
                                                    float* __restrict__ stats) {
    const int ch = blockIdx.x;   // 0..127
    const float* pS = partials + (size_t)ch * 4096;
    const float* pQ = partials + (size_t)(CH + ch) * 4096;
    float s = 0.0f, q = 0.0f;
    for (int i = threadIdx.x; i < 4096; i += 256) { s += pS[i]; q += pQ[i]; }
#pragma unroll
    for (int off = 32; off > 0; off >>= 1) {
        s += __shfl_down(s, off);
        q += __shfl_down(q, off);
    }
    __shared__ float wsum[4][2];
    const int wid = threadIdx.x >> 6;
    if ((threadIdx.x & 63) == 0) { wsum[wid][0] = s; wsum[wid][1] = q; }
    __syncthreads();
    if (threadIdx.x == 0) {
        const float S = wsum[0][0] + wsum[1][0] + wsum[2][0] + wsum[3][0];
        const float Q = wsum[0][1] + wsum[1][1] + wsum[2][1] + wsum[3][1];
        const float inv  = 1.0f / (float)(BATCH * NPTS);
        const float mean = S * inv;
        const float var  = Q * inv - mean * mean;
        stats[ch]      = mean;
        stats[CH + ch] = rsqrtf(var + 1e-5f);
    }
}

// ---------------------------------------------------------------------------
// 5) out[b,c,n] = x + gamma*(h - mean)*rstd + beta   (h stored [B,N,CH])
__global__ __launch_bounds__(256) void final_kernel(const float* __restrict__ x,
                                                    const float* __restrict__ h_t,
                                                    const float* __restrict__ stats,
                                                    const float* __restrict__ gamma,
                                                    const float* __restrict__ beta,
                                                    float* __restrict__ out) {
    __shared__ float t[32][33];
    const int b  = blockIdx.z;
    const int o0 = blockIdx.y * 32;
    const int n0 = blockIdx.x * 32;
    const int tx = threadIdx.x, ty = threadIdx.y;   // block (32,8)
#pragma unroll
    for (int i = 0; i < 4; ++i)
        t[ty + 8 * i][tx] = h_t[((size_t)b * NPTS + n0 + ty + 8 * i) * CH + o0 + tx];
    __syncthreads();
#pragma unroll
    for (int i = 0; i < 4; ++i) {
        const int o = o0 + ty + 8 * i;
        const float mean = stats[o];
        const float rstd = stats[CH + o];
        const float g = gamma[o], be = beta[o];
        const size_t offp = ((size_t)b * CH + o) * NPTS + n0 + tx;
        out[offp] = x[offp] + g * ((t[tx][ty + 8 * i] - mean) * rstd) + be;
    }
}

// ---------------------------------------------------------------------------
extern "C" void kernel_launch(void* const* d_in, const int* in_sizes, int n_in,
                              void* d_out, int out_size, void* d_ws, size_t ws_size,
                              hipStream_t stream) {
    const float* xyz    = (const float*)d_in[0];
    const float* x      = (const float*)d_in[1];
    const float* conv_w = (const float*)d_in[2];
    const float* conv_b = (const float*)d_in[3];
    const float* gamma  = (const float*)d_in[4];
    const float* beta   = (const float*)d_in[5];
    float* out = (float*)d_out;

    char* ws = (char*)d_ws;
    float*        xt     = (float*)(ws + XT_OFF);
    int*          counts = (int*)  (ws + CNT_OFF);
    int*          cursor = (int*)  (ws + CUR_OFF);
    int2*         hdr    = (int2*) (ws + HDR_OFF);
    int2*         hdrc   = (int2*) (ws + HDRC_OFF);
    unsigned int* occ    = (unsigned int*)(ws + OCC_OFF);
    unsigned int* soccc  = (unsigned int*)(ws + SOCCC_OFF);
    float4*       spts   = (float4*)(ws + SPTS_OFF);
    int*          gctr   = (int*)  (ws + GCTR_OFF);
    float*        h_t    = (float*)(ws + HT_OFF);
    int*          idx    = (int*)  (ws + IDX_OFF);
    float*        part   = (float*)(ws + PART_OFF);
    float*        stats  = (float*)(ws + STATS_OFF);

    // feature transpose (independent of grid work)
    transpose_kernel<<<dim3(NPTS / 32, CH / 32, BATCH), dim3(32, 8), 0, stream>>>(x, xt);

    // grid build (two-level)
    zero_kernel<<<dim3(2048), dim3(256), 0, stream>>>(counts, 2 * BATCH * GRID3,
                                                      (int*)soccc, BATCH * CROWS, gctr);
    count_kernel<<<dim3(NPTS / 256, BATCH), dim3(256), 0, stream>>>(xyz, counts);
    cellhdr_kernel<<<dim3(BATCH * GRID3 / 256), dim3(256), 0, stream>>>(counts, hdr, hdrc, soccc, gctr);
    occ_kernel<<<dim3(BATCH * GRID3 / 256), dim3(256), 0, stream>>>(counts, occ);
    scatter_kernel<<<dim3(NPTS / 256, BATCH), dim3(256), 0, stream>>>(xyz, hdr, cursor, spts);

    // exact knn (serial walk, two-level)
    knn_grid_kernel<<<dim3(NPTS / 256, BATCH), dim3(256), 0, stream>>>(spts, hdr, hdrc, occ, soccc, idx);

    // gather + conv + relu + partial BN sums (overwrites grid region with h_t)
    conv_kernel<<<dim3(BATCH * NPTS / 16), dim3(128), 0, stream>>>(xt, idx, conv_w, conv_b, h_t, part);
    bnred_kernel<<<dim3(CH), dim3(256), 0, stream>>>(part, stats);
    final_kernel<<<dim3(NPTS / 32, CH / 32, BATCH), dim3(32, 8), 0, stream>>>(x, h_t, stats, gamma, beta, out);
}

// Round 9
// 986.880 us; speedup vs baseline: 2.3731x; 1.5364x over previous
//
#include <hip/hip_runtime.h>

#define BATCH 4
#define NPTS  16384
#define CH    128
#define KNN   16

// ---- fine grid: 64^3 cells of 0.25 ----
#define G      64
#define GRID3  (G * G * G)          // 262144 cells per batch (= 2^18)
#define GW     0.25f
#define GINVW  4.0f
#define GORIG  (-8.0f)
#define OCCW   (GRID3 / 32)         // 8192 occupancy words per batch

// ---------------- workspace layout (bytes) ----------------
// xt    : [B][N][CH] float     off 0            33,554,432
// grid region (reused later by h_t, written only after knn done):
//   counts : [B][G^3] int      off 33554432      4,194,304
//   cursor : [B][G^3] int      off 37748736      4,194,304
//   hdr    : [B][G^3] int2     off 41943040      8,388,608   (linear cid)
//   occ    : [B][8192] uint    off 50331648        131,072   (z-major rows, x bits)
//   occX   : [B][8192] uint    off 50462720        131,072   (x-major rows, y bits)
//   spts   : [B][N] float4     off 50593792      1,048,576
//   gctr   : [B] int           off 51642368             16
// idx   : [B][N][16] int       off 67108864      4,194,304
// part  : [256][4096] float    off 71303168      4,194,304
// stats : [256] float          off 75497472          1,024
#define XT_OFF    0
#define HT_OFF    33554432
#define CNT_OFF   33554432
#define CUR_OFF   37748736
#define HDR_OFF   41943040
#define OCC_OFF   50331648
#define OCCX_OFF  50462720
#define SPTS_OFF  50593792
#define GCTR_OFF  51642368
#define IDX_OFF   67108864
#define PART_OFF  71303168
#define STATS_OFF 75497472

__device__ __forceinline__ int cell1(float v) {
    int c = (int)floorf((v - GORIG) * GINVW);
    return min(G - 1, max(0, c));
}

// min distance from coordinate q to cell slab [GORIG + c*GW, GORIG + (c+1)*GW]
__device__ __forceinline__ float axdist(float q, int c) {
    const float lo = GORIG + c * GW;
    return fmaxf(fmaxf(lo - q, q - (lo + GW)), 0.0f);
}

__device__ __forceinline__ bool lexlt(float d1, int i1, float d2, int i2) {
    return (d1 < d2) || (d1 == d2 && i1 < i2);
}

__device__ __forceinline__ void insert_lex(float (&dq)[KNN], int (&iq)[KNN], float d, int oi) {
    if (!lexlt(d, oi, dq[KNN - 1], iq[KNN - 1])) return;
    float cd = d; int ci = oi;
#pragma unroll
    for (int t = KNN - 1; t >= 1; --t) {
        if (lexlt(cd, ci, dq[t - 1], iq[t - 1])) {
            dq[t] = dq[t - 1]; iq[t] = iq[t - 1];
            if (t == 1) { dq[0] = cd; iq[0] = ci; }
        } else {
            dq[t] = cd; iq[t] = ci;
            break;
        }
    }
}

__device__ __forceinline__ void scan_cell(const float4* __restrict__ pts, int st, int en,
                                          float qx, float qy, float qz,
                                          float (&dq)[KNN], int (&iq)[KNN]) {
    for (int j = st; j < en; ++j) {
        const float4 pp = pts[j];
        const float ddx = __fsub_rn(qx, pp.x);
        const float ddy = __fsub_rn(qy, pp.y);
        const float ddz = __fsub_rn(qz, pp.z);
        const float d = __fadd_rn(__fadd_rn(__fmul_rn(ddx, ddx), __fmul_rn(ddy, ddy)),
                                  __fmul_rn(ddz, ddz));
        insert_lex(dq, iq, d, __float_as_int(pp.w));
    }
}

// ---------------------------------------------------------------------------
// 0) zero grid counters (counts+cursor contiguous) and per-batch allocators
__global__ __launch_bounds__(256) void zero_kernel(int* __restrict__ p, int n,
                                                   int* __restrict__ gctr) {
    int i = blockIdx.x * 256 + threadIdx.x;
    if (i < BATCH) gctr[i] = 0;
    const int stride = gridDim.x * 256;
    for (; i < n; i += stride) p[i] = 0;
}

// ---------------------------------------------------------------------------
// 1) transpose x [B,CH,N] -> xt [B,N,CH]
__global__ __launch_bounds__(256) void transpose_kernel(const float* __restrict__ x,
                                                        float* __restrict__ xt) {
    __shared__ float t[32][33];
    const int b  = blockIdx.z;
    const int c0 = blockIdx.y * 32;
    const int n0 = blockIdx.x * 32;
    const int tx = threadIdx.x, ty = threadIdx.y;   // block (32,8)
#pragma unroll
    for (int i = 0; i < 4; ++i)
        t[ty + 8 * i][tx] = x[((size_t)b * CH + c0 + ty + 8 * i) * NPTS + n0 + tx];
    __syncthreads();
#pragma unroll
    for (int i = 0; i < 4; ++i)
        xt[((size_t)b * NPTS + n0 + ty + 8 * i) * CH + c0 + tx] = t[tx][ty + 8 * i];
}

// ---------------------------------------------------------------------------
// 2a) count points per cell (linear cid = (z*G+y)*G+x)
__global__ __launch_bounds__(256) void count_kernel(const float* __restrict__ xyz,
                                                    int* __restrict__ counts) {
    const int b = blockIdx.y;
    const int i = blockIdx.x * 256 + threadIdx.x;
    const float* p = xyz + ((size_t)b * NPTS + i) * 3;
    const int c = (cell1(p[2]) * G + cell1(p[1])) * G + cell1(p[0]);
    atomicAdd(&counts[((size_t)b << 18) + c], 1);
}

// 2b) per-cell (start,count) headers + z-major occupancy via wave-aggregated
//     atomic allocation. Start order nondeterministic, but knn selection is
//     lexicographic (d, original idx) -> output exact.
__global__ __launch_bounds__(256) void cellhdr_kernel(const int* __restrict__ counts,
                                                      int2* __restrict__ hdr,
                                                      unsigned int* __restrict__ occ,
                                                      int* __restrict__ gctr) {
    const int cid  = blockIdx.x * 256 + threadIdx.x;   // 0 .. B*GRID3-1
    const int b    = cid >> 18;
    const int lane = threadIdx.x & 63;
    const int c    = counts[cid];

    int incl = c;
#pragma unroll
    for (int off = 1; off < 64; off <<= 1) {
        int t = __shfl_up(incl, off);
        if (lane >= off) incl += t;
    }
    const int excl = incl - c;
    const int tot  = __shfl(incl, 63);

    const unsigned long long ball = __ballot(c > 0);
    if (lane == 0) {
        const int w = cid >> 5;
        occ[w]     = (unsigned int)ball;
        occ[w + 1] = (unsigned int)(ball >> 32);
    }

    int base = 0;
    if (lane == 63) base = atomicAdd(&gctr[b], tot);
    base = __shfl(base, 63);

    if (c > 0) hdr[cid] = make_int2(base + excl, c);
}

// 2c) x-major occupancy: row = x*G+z, bits = y
__global__ __launch_bounds__(256) void occx_kernel(const int* __restrict__ counts,
                                                   unsigned int* __restrict__ occX) {
    const int gid = blockIdx.x * 256 + threadIdx.x;    // b<<18 | x<<12 | z<<6 | y
    const int b   = gid >> 18;
    const int lin = gid & (GRID3 - 1);
    const int x = lin >> 12, z = (lin >> 6) & 63, y = lin & 63;
    const int c = counts[((size_t)b << 18) + ((z * G + y) * G + x)];
    const unsigned long long ball = __ballot(c > 0);
    if ((threadIdx.x & 63) == 0) {
        const int row = gid >> 6;                      // b*4096 + x*64 + z
        occX[row * 2]     = (unsigned int)ball;
        occX[row * 2 + 1] = (unsigned int)(ball >> 32);
    }
}

// 2d) scatter points into cell-grouped order, original idx in .w
__global__ __launch_bounds__(256) void scatter_kernel(const float* __restrict__ xyz,
                                                      const int2* __restrict__ hdr,
                                                      int* __restrict__ cursor,
                                                      float4* __restrict__ spts) {
    const int b = blockIdx.y;
    const int i = blockIdx.x * 256 + threadIdx.x;
    const float* p = xyz + ((size_t)b * NPTS + i) * 3;
    const float x = p[0], y = p[1], z = p[2];
    const int c = (cell1(z) * G + cell1(y)) * G + cell1(x);
    const int pos = hdr[((size_t)b << 18) + c].x + atomicAdd(&cursor[((size_t)b << 18) + c], 1);
    spts[(size_t)b * NPTS + pos] = make_float4(x, y, z, __int_as_float(i));
}

// ---------------------------------------------------------------------------
// 2e) exact KNN, serial walk per thread, SHELL-ONLY ring iteration:
//     z-faces + y-faces via z-major occ, x-faces via x-major occX.
//     Seed bound B0 (16th order stat of a 64-candidate subset, distances only,
//     discarded) gives conservative pruning from ring 1. Output exact lex.
__global__ __launch_bounds__(256) void knn_grid_kernel(const float4* __restrict__ spts,
                                                       const int2* __restrict__ hdr,
                                                       const unsigned int* __restrict__ occ,
                                                       const unsigned int* __restrict__ occX,
                                                       int* __restrict__ idx_out) {
    __shared__ unsigned int socc[OCCW];     // 32 KB z-major occupancy
    __shared__ unsigned int soccX[OCCW];    // 32 KB x-major occupancy
    const int b   = blockIdx.y;
    const int tid = threadIdx.x;
    for (int i = tid; i < OCCW; i += 256) {
        socc[i]  = occ [(size_t)b * OCCW + i];
        soccX[i] = occX[(size_t)b * OCCW + i];
    }
    __syncthreads();

    const int s = blockIdx.x * 256 + tid;
    const float4 P = spts[(size_t)b * NPTS + s];
    const float qx = P.x, qy = P.y, qz = P.z;
    const int qi = __float_as_int(P.w);
    const int cx = cell1(qx), cy = cell1(qy), cz = cell1(qz);
    const int2* hb = hdr + ((size_t)b << 18);
    const float4* pts = spts + (size_t)b * NPTS;

    // ---- seed bound: 16th smallest distance among 64 window candidates ----
    float sd[KNN];
#pragma unroll
    for (int t = 0; t < KNN; ++t) sd[t] = 3.0e38f;
    {
        int w0 = s - 24;
        w0 = max(0, min(w0, NPTS - 64));
        for (int j = w0; j < w0 + 64; ++j) {
            const float4 pp = pts[j];
            const float ddx = __fsub_rn(qx, pp.x);
            const float ddy = __fsub_rn(qy, pp.y);
            const float ddz = __fsub_rn(qz, pp.z);
            const float d = __fadd_rn(__fadd_rn(__fmul_rn(ddx, ddx), __fmul_rn(ddy, ddy)),
                                      __fmul_rn(ddz, ddz));
            if (d < sd[KNN - 1]) {
                float cd = d;
#pragma unroll
                for (int t = KNN - 1; t >= 1; --t) {
                    if (cd < sd[t - 1]) { sd[t] = sd[t - 1]; if (t == 1) sd[0] = cd; }
                    else { sd[t] = cd; break; }
                }
            }
        }
    }
    const float B0 = sd[KNN - 1];   // valid upper bound on true d16

    float dq[KNN]; int iq[KNN];
#pragma unroll
    for (int t = 0; t < KNN; ++t) { dq[t] = 3.0e38f; iq[t] = 0x7fffffff; }

    // ring 0: center cell
    {
        const int2 hc = hb[(cz * G + cy) * G + cx];
        scan_cell(pts, hc.x, hc.x + hc.y, qx, qy, qz, dq, iq);
    }

    for (int R = 1; R < G; ++R) {
        // termination: processed box = rings 0..R-1
        {
            const int rm = R - 1;
            const float bound = fminf(B0, dq[KNN - 1]);
            float dmin = 3.0e38f;
            bool any = false;
            if (cx - rm > 0)     { dmin = fminf(dmin, qx - (GORIG + (cx - rm) * GW)); any = true; }
            if (cx + rm < G - 1) { dmin = fminf(dmin, (GORIG + (cx + rm + 1) * GW) - qx); any = true; }
            if (cy - rm > 0)     { dmin = fminf(dmin, qy - (GORIG + (cy - rm) * GW)); any = true; }
            if (cy + rm < G - 1) { dmin = fminf(dmin, (GORIG + (cy + rm + 1) * GW) - qy); any = true; }
            if (cz - rm > 0)     { dmin = fminf(dmin, qz - (GORIG + (cz - rm) * GW)); any = true; }
            if (cz + rm < G - 1) { dmin = fminf(dmin, (GORIG + (cz + rm + 1) * GW) - qz); any = true; }
            if (!any) break;
            dmin = fmaxf(dmin, 0.0f);
            if (bound < dmin * dmin * (1.0f - 1e-5f)) break;
        }
        const int z0 = max(0, cz - R), z1 = min(G - 1, cz + R);
        const int y0 = max(0, cy - R), y1 = min(G - 1, cy + R);
        const int x0 = max(0, cx - R), x1 = min(G - 1, cx + R);
        const int zi0 = max(z0, cz - R + 1), zi1 = min(z1, cz + R - 1);
        const int yi0 = max(y0, cy - R + 1), yi1 = min(y1, cy + R - 1);
        const unsigned long long xm_full = (~0ull >> (63 - (x1 - x0))) << x0;

        // ---- z-faces (az == R): all y, x ----
#pragma unroll
        for (int f = 0; f < 2; ++f) {
            const int z = f ? cz + R : cz - R;
            if (z < 0 || z > G - 1) continue;
            const float dzc = axdist(qz, z);
            const float dz2 = dzc * dzc;
            for (int y = y0; y <= y1; ++y) {
                const float dyc = axdist(qy, y);
                const float dzy = dz2 + dyc * dyc;
                if (dzy * (1.0f - 1e-5f) > fminf(B0, dq[KNN - 1])) continue;
                const int row = z * G + y;
                unsigned long long m = xm_full &
                    ((unsigned long long)socc[row * 2] |
                     ((unsigned long long)socc[row * 2 + 1] << 32));
                while (m) {
                    const int x = __ffsll(m) - 1;
                    m &= m - 1;
                    const float dxc = axdist(qx, x);
                    const float cmin = dzy + dxc * dxc;
                    if (cmin * (1.0f - 1e-5f) > fminf(B0, dq[KNN - 1])) continue;
                    const int2 hc = hb[row * G + x];
                    scan_cell(pts, hc.x, hc.x + hc.y, qx, qy, qz, dq, iq);
                }
            }
        }
        // ---- y-faces (ay == R, az < R): interior z, all x ----
#pragma unroll
        for (int f = 0; f < 2; ++f) {
            const int y = f ? cy + R : cy - R;
            if (y < 0 || y > G - 1) continue;
            const float dyc = axdist(qy, y);
            const float dy2 = dyc * dyc;
            for (int z = zi0; z <= zi1; ++z) {
                const float dzc = axdist(qz, z);
                const float dzy = dzc * dzc + dy2;
                if (dzy * (1.0f - 1e-5f) > fminf(B0, dq[KNN - 1])) continue;
                const int row = z * G + y;
                unsigned long long m = xm_full &
                    ((unsigned long long)socc[row * 2] |
                     ((unsigned long long)socc[row * 2 + 1] << 32));
                while (m) {
                    const int x = __ffsll(m) - 1;
                    m &= m - 1;
                    const float dxc = axdist(qx, x);
                    const float cmin = dzy + dxc * dxc;
                    if (cmin * (1.0f - 1e-5f) > fminf(B0, dq[KNN - 1])) continue;
                    const int2 hc = hb[row * G + x];
                    scan_cell(pts, hc.x, hc.x + hc.y, qx, qy, qz, dq, iq);
                }
            }
        }
        // ---- x-faces (ax == R, az < R, ay < R): interior z and y ----
        {
            const unsigned long long ym_full = (~0ull >> (63 - (yi1 - yi0))) << yi0;
#pragma unroll
            for (int f = 0; f < 2; ++f) {
                const int x = f ? cx + R : cx - R;
                if (x < 0 || x > G - 1) continue;
                const float dxc = axdist(qx, x);
                const float dx2 = dxc * dxc;
                for (int z = zi0; z <= zi1; ++z) {
                    const float dzc = axdist(qz, z);
                    const float dxz = dx2 + dzc * dzc;
                    if (dxz * (1.0f - 1e-5f) > fminf(B0, dq[KNN - 1])) continue;
                    const int rowx = x * G + z;
                    unsigned long long m = ym_full &
                        ((unsigned long long)soccX[rowx * 2] |
                         ((unsigned long long)soccX[rowx * 2 + 1] << 32));
                    while (m) {
                        const int y = __ffsll(m) - 1;
                        m &= m - 1;
                        const float dyc = axdist(qy, y);
                        const float cmin = dxz + dyc * dyc;
                        if (cmin * (1.0f - 1e-5f) > fminf(B0, dq[KNN - 1])) continue;
                        const int2 hc = hb[(z * G + y) * G + x];
                        scan_cell(pts, hc.x, hc.x + hc.y, qx, qy, qz, dq, iq);
                    }
                }
            }
        }
    }

    int* op = idx_out + ((size_t)b * NPTS + qi) * KNN;
#pragma unroll
    for (int t = 0; t < KNN; ++t) op[t] = iq[t];
}

// ---------------------------------------------------------------------------
// 3) gather + Laplacian dx + 1x1 conv + relu + BN partial sums.
__global__ __launch_bounds__(128) void conv_kernel(const float* __restrict__ xt,
                                                   const int* __restrict__ idx,
                                                   const float* __restrict__ W,
                                                   const float* __restrict__ bias,
                                                   float* __restrict__ h_t,
                                                   float* __restrict__ partials) {
    __shared__ __align__(16) float dxbuf[CH];
    const int o   = threadIdx.x;
    const int blk = blockIdx.x;                  // 0..4095
    const int b   = blk / (NPTS / 16);
    const int n0  = (blk % (NPTS / 16)) * 16;

    float4 w4[CH / 4];
    const float4* wrow = (const float4*)(W + (size_t)o * CH);
#pragma unroll
    for (int i = 0; i < CH / 4; ++i) w4[i] = wrow[i];
    const float bo = bias[o];

    const float* xb = xt + (size_t)b * NPTS * CH;
    float sS = 0.0f, sQ = 0.0f;

    for (int r = 0; r < 16; ++r) {
        const int n = n0 + r;
        const int* ip = idx + ((size_t)b * NPTS + n) * KNN;
        int jj[KNN];
#pragma unroll
        for (int k = 0; k < KNN; ++k) jj[k] = ip[k];
        float va[KNN];
#pragma unroll
        for (int k = 0; k < KNN; ++k) va[k] = xb[(size_t)jj[k] * CH + o];
        const float ctr = xb[(size_t)n * CH + o];
        float acc = 0.0f;
#pragma unroll
        for (int k = 0; k < KNN; ++k) acc += va[k];
        acc -= ctr;

        dxbuf[o] = acc;
        __syncthreads();

        float h = bo;
        const float4* d4 = (const float4*)dxbuf;
#pragma unroll
        for (int cc = 0; cc < CH / 4; ++cc) {
            const float4 a = d4[cc];
            const float4 w = w4[cc];
            h = fmaf(w.x, a.x, h);
            h = fmaf(w.y, a.y, h);
            h = fmaf(w.z, a.z, h);
            h = fmaf(w.w, a.w, h);
        }
        h = fmaxf(h, 0.0f);
        h_t[((size_t)b * NPTS + n) * CH + o] = h;
        sS += h;
        sQ += h * h;
        __syncthreads();
    }

    partials[(size_t)o * 4096 + blk]        = sS;
    partials[(size_t)(CH + o) * 4096 + blk] = sQ;
}

// ---------------------------------------------------------------------------
// 4) reduce partials -> mean / rstd per channel (deterministic)
__global__ __launch_bounds__(256) void bnred_kernel(const float* __restrict__ partials,
                                                    float* __restrict__ stats) {
    const int ch = blockIdx.x;   // 0..127
    const float* pS = partials + (size_t)ch * 4096;
    const float* pQ = partials + (size_t)(CH + ch) * 4096;
    float s = 0.0f, q = 0.0f;
    for (int i = threadIdx.x; i < 4096; i += 256) { s += pS[i]; q += pQ[i]; }
#pragma unroll
    for (int off = 32; off > 0; off >>= 1) {
        s += __shfl_down(s, off);
        q += __shfl_down(q, off);
    }
    __shared__ float wsum[4][2];
    const int wid = threadIdx.x >> 6;
    if ((threadIdx.x & 63) == 0) { wsum[wid][0] = s; wsum[wid][1] = q; }
    __syncthreads();
    if (threadIdx.x == 0) {
        const float S = wsum[0][0] + wsum[1][0] + wsum[2][0] + wsum[3][0];
        const float Q = wsum[0][1] + wsum[1][1] + wsum[2][1] + wsum[3][1];
        const float inv  = 1.0f / (float)(BATCH * NPTS);
        const float mean = S * inv;
        const float var  = Q * inv - mean * mean;
        stats[ch]      = mean;
        stats[CH + ch] = rsqrtf(var + 1e-5f);
    }
}

// ---------------------------------------------------------------------------
// 5) out[b,c,n] = x + gamma*(h - mean)*rstd + beta   (h stored [B,N,CH])
__global__ __launch_bounds__(256) void final_kernel(const float* __restrict__ x,
                                                    const float* __restrict__ h_t,
                                                    const float* __restrict__ stats,
                                                    const float* __restrict__ gamma,
                                                    const float* __restrict__ beta,
                                                    float* __restrict__ out) {
    __shared__ float t[32][33];
    const int b  = blockIdx.z;
    const int o0 = blockIdx.y * 32;
    const int n0 = blockIdx.x * 32;
    const int tx = threadIdx.x, ty = threadIdx.y;   // block (32,8)
#pragma unroll
    for (int i = 0; i < 4; ++i)
        t[ty + 8 * i][tx] = h_t[((size_t)b * NPTS + n0 + ty + 8 * i) * CH + o0 + tx];
    __syncthreads();
#pragma unroll
    for (int i = 0; i < 4; ++i) {
        const int o = o0 + ty + 8 * i;
        const float mean = stats[o];
        const float rstd = stats[CH + o];
        const float g = gamma[o], be = beta[o];
        const size_t offp = ((size_t)b * CH + o) * NPTS + n0 + tx;
        out[offp] = x[offp] + g * ((t[tx][ty + 8 * i] - mean) * rstd) + be;
    }
}

// ---------------------------------------------------------------------------
extern "C" void kernel_launch(void* const* d_in, const int* in_sizes, int n_in,
                              void* d_out, int out_size, void* d_ws, size_t ws_size,
                              hipStream_t stream) {
    const float* xyz    = (const float*)d_in[0];
    const float* x      = (const float*)d_in[1];
    const float* conv_w = (const float*)d_in[2];
    const float* conv_b = (const float*)d_in[3];
    const float* gamma  = (const float*)d_in[4];
    const float* beta   = (const float*)d_in[5];
    float* out = (float*)d_out;

    char* ws = (char*)d_ws;
    float*        xt     = (float*)(ws + XT_OFF);
    int*          counts = (int*)  (ws + CNT_OFF);
    int*          cursor = (int*)  (ws + CUR_OFF);
    int2*         hdr    = (int2*) (ws + HDR_OFF);
    unsigned int* occ    = (unsigned int*)(ws + OCC_OFF);
    unsigned int* occX   = (unsigned int*)(ws + OCCX_OFF);
    float4*       spts   = (float4*)(ws + SPTS_OFF);
    int*          gctr   = (int*)  (ws + GCTR_OFF);
    float*        h_t    = (float*)(ws + HT_OFF);
    int*          idx    = (int*)  (ws + IDX_OFF);
    float*        part   = (float*)(ws + PART_OFF);
    float*        stats  = (float*)(ws + STATS_OFF);

    // feature transpose (independent of grid work)
    transpose_kernel<<<dim3(NPTS / 32, CH / 32, BATCH), dim3(32, 8), 0, stream>>>(x, xt);

    // grid build
    zero_kernel<<<dim3(2048), dim3(256), 0, stream>>>(counts, 2 * BATCH * GRID3, gctr);
    count_kernel<<<dim3(NPTS / 256, BATCH), dim3(256), 0, stream>>>(xyz, counts);
    cellhdr_kernel<<<dim3(BATCH * GRID3 / 256), dim3(256), 0, stream>>>(counts, hdr, occ, gctr);
    occx_kernel<<<dim3(BATCH * GRID3 / 256), dim3(256), 0, stream>>>(counts, occX);
    scatter_kernel<<<dim3(NPTS / 256, BATCH), dim3(256), 0, stream>>>(xyz, hdr, cursor, spts);

    // exact knn (serial walk, shell-only rings, seed bound)
    knn_grid_kernel<<<dim3(NPTS / 256, BATCH), dim3(256), 0, stream>>>(spts, hdr, occ, occX, idx);

    // gather + conv + relu + partial BN sums (overwrites grid region with h_t)
    conv_kernel<<<dim3(BATCH * NPTS / 16), dim3(128), 0, stream>>>(xt, idx, conv_w, conv_b, h_t, part);
    bnred_kernel<<<dim3(CH), dim3(256), 0, stream>>>(part, stats);
    final_kernel<<<dim3(NPTS / 32, CH / 32, BATCH), dim3(32, 8), 0, stream>>>(x, h_t, stats, gamma, beta, out);
}